// Round 1
// baseline (286.345 us; speedup 1.0000x reference)
//
#include <hip/hip_runtime.h>
#include <hip/hip_bf16.h>

#define NN 8192
#define CIN 32
#define COUT 64
#define KF 5
#define SPLITS 8

typedef __attribute__((ext_vector_type(8))) short bf16x8_t;
typedef __attribute__((ext_vector_type(4))) float f32x4_t;

// fp32 -> bf16 RNE (no NaN handling; inputs are finite Gaussians)
__device__ __forceinline__ short f2bf(float f) {
    unsigned u = __builtin_bit_cast(unsigned, f);
    unsigned r = (u + 0x7FFFu + ((u >> 16) & 1u)) >> 16;
    return (short)(unsigned short)r;
}

// Convert fp32 array -> bf16 (short) array, 4 elements/thread
__global__ void cvt_kernel(const float* __restrict__ src, short* __restrict__ dst, int n4) {
    int idx = blockIdx.x * blockDim.x + threadIdx.x;
    if (idx >= n4) return;
    float4 v = reinterpret_cast<const float4*>(src)[idx];
    short4 b;
    b.x = f2bf(v.x); b.y = f2bf(v.y); b.z = f2bf(v.z); b.w = f2bf(v.w);
    reinterpret_cast<short4*>(dst)[idx] = b;
}

// One Chebyshev GEMM pass (split-K partials):
//   part[s][c][i] = sum_{j in chunk s} Tcur_bf16[c][j] * bf16(L[i][j])
// Block = 4 waves; wave w owns i-tile [blockIdx.x*64 + w*16, +16), all 32 channels.
// MFMA 16x16x32 bf16: A = Tcur rows (M=c), B = L rows (N=i), K=j.
__global__ __launch_bounds__(256, 4) void cheb_pass_kernel(
    const float* __restrict__ L,
    const short* __restrict__ Tcur,   // CIN x NN bf16
    float* __restrict__ part)         // SPLITS x CIN x NN fp32
{
    const int lane = threadIdx.x & 63;
    const int wave = threadIdx.x >> 6;
    const int g = lane >> 4;          // 0..3 (k-chunk group)
    const int r = lane & 15;          // row-within-16
    const int i0 = blockIdx.x * 64 + wave * 16;
    const int s = blockIdx.y;
    const int jb = s * (NN / SPLITS);

    const float* Lrow = L + (size_t)(i0 + r) * NN;

    f32x4_t acc0 = {0.f, 0.f, 0.f, 0.f};
    f32x4_t acc1 = {0.f, 0.f, 0.f, 0.f};

    for (int j = jb; j < jb + NN / SPLITS; j += 32) {
        const int jl = j + g * 8;
        // B fragment: 8 contiguous fp32 from L row (i0+r), convert to bf16
        float4 l0 = *reinterpret_cast<const float4*>(Lrow + jl);
        float4 l1 = *reinterpret_cast<const float4*>(Lrow + jl + 4);
        bf16x8_t b;
        b[0] = f2bf(l0.x); b[1] = f2bf(l0.y); b[2] = f2bf(l0.z); b[3] = f2bf(l0.w);
        b[4] = f2bf(l1.x); b[5] = f2bf(l1.y); b[6] = f2bf(l1.z); b[7] = f2bf(l1.w);
        // A fragments: Tcur rows r and r+16, 8 contiguous bf16 (16B aligned)
        bf16x8_t a0 = *reinterpret_cast<const bf16x8_t*>(Tcur + (size_t)r * NN + jl);
        bf16x8_t a1 = *reinterpret_cast<const bf16x8_t*>(Tcur + (size_t)(r + 16) * NN + jl);
        acc0 = __builtin_amdgcn_mfma_f32_16x16x32_bf16(a0, b, acc0, 0, 0, 0);
        acc1 = __builtin_amdgcn_mfma_f32_16x16x32_bf16(a1, b, acc1, 0, 0, 0);
    }

    // D layout (m89-verified): col = lane&15 -> i, row = (lane>>4)*4 + reg -> c
    float* pbase = part + (size_t)s * CIN * NN + i0 + r;
#pragma unroll
    for (int t = 0; t < 4; ++t) {
        pbase[(size_t)(g * 4 + t) * NN]      = acc0[t];
        pbase[(size_t)(g * 4 + t + 16) * NN] = acc1[t];
    }
}

// T_next = alpha * sum_s part[s] - (has_prev ? T_prev : 0); write fp32 + bf16
__global__ void combine_kernel(const float* __restrict__ part,
                               const float* __restrict__ Tprev,
                               const float alpha, const int has_prev,
                               float* __restrict__ Tf, short* __restrict__ Tb)
{
    int idx = blockIdx.x * blockDim.x + threadIdx.x;  // quad index over CIN*NN/4
    if (idx >= CIN * NN / 4) return;
    const float4* p = reinterpret_cast<const float4*>(part);
    float4 sv = p[idx];
#pragma unroll
    for (int t = 1; t < SPLITS; ++t) {
        float4 v = p[(size_t)t * (CIN * NN / 4) + idx];
        sv.x += v.x; sv.y += v.y; sv.z += v.z; sv.w += v.w;
    }
    sv.x *= alpha; sv.y *= alpha; sv.z *= alpha; sv.w *= alpha;
    if (has_prev) {
        float4 pv = reinterpret_cast<const float4*>(Tprev)[idx];
        sv.x -= pv.x; sv.y -= pv.y; sv.z -= pv.z; sv.w -= pv.w;
    }
    reinterpret_cast<float4*>(Tf)[idx] = sv;
    short4 b;
    b.x = f2bf(sv.x); b.y = f2bf(sv.y); b.z = f2bf(sv.z); b.w = f2bf(sv.w);
    reinterpret_cast<short4*>(Tb)[idx] = b;
}

// y(o,i) = bias(o) + sum_{c,k} T_k(c,i) * theta(o,c,k); 4 o's per thread
__global__ __launch_bounds__(256) void final_kernel(
    const float* __restrict__ x,   // T0 (fp32, exact)
    const float* __restrict__ T1, const float* __restrict__ T2,
    const float* __restrict__ T3, const float* __restrict__ T4,
    const float* __restrict__ theta, const float* __restrict__ bias,
    float* __restrict__ y)
{
    __shared__ float th[4 * CIN * KF];  // theta slice for this block's 4 o's
    int idx = blockIdx.x * blockDim.x + threadIdx.x;
    int i = idx & (NN - 1);
    int og = idx >> 13;               // 0..15 (block-uniform: 32 blocks per og)
    for (int t = threadIdx.x; t < 4 * CIN * KF; t += blockDim.x)
        th[t] = theta[og * 4 * CIN * KF + t];
    __syncthreads();

    float a0 = bias[og * 4 + 0], a1 = bias[og * 4 + 1];
    float a2 = bias[og * 4 + 2], a3 = bias[og * 4 + 3];
    for (int c = 0; c < CIN; ++c) {
        size_t o = (size_t)c * NN + i;
        float t0 = x[o], t1 = T1[o], t2 = T2[o], t3 = T3[o], t4 = T4[o];
#pragma unroll
        for (int oo = 0; oo < 4; ++oo) {
            const float* tc = &th[(oo * CIN + c) * KF];
            float v = t0 * tc[0] + t1 * tc[1] + t2 * tc[2] + t3 * tc[3] + t4 * tc[4];
            if (oo == 0) a0 += v; else if (oo == 1) a1 += v;
            else if (oo == 2) a2 += v; else a3 += v;
        }
    }
    y[(size_t)(og * 4 + 0) * NN + i] = a0;
    y[(size_t)(og * 4 + 1) * NN + i] = a1;
    y[(size_t)(og * 4 + 2) * NN + i] = a2;
    y[(size_t)(og * 4 + 3) * NN + i] = a3;
}

extern "C" void kernel_launch(void* const* d_in, const int* in_sizes, int n_in,
                              void* d_out, int out_size, void* d_ws, size_t ws_size,
                              hipStream_t stream) {
    const float* L     = (const float*)d_in[0];
    const float* x     = (const float*)d_in[1];
    const float* theta = (const float*)d_in[2];
    const float* bias  = (const float*)d_in[3];
    float* y = (float*)d_out;

    // Workspace layout (~14.5 MB):
    //   part: SPLITS*CIN*NN fp32 (8 MB)
    //   Tf1..Tf4: CIN*NN fp32 each (4 MB)
    //   Tb0..Tb4: CIN*NN bf16 each (2.5 MB)
    const size_t TE = (size_t)CIN * NN;
    float* part = (float*)d_ws;
    float* Tf1 = part + (size_t)SPLITS * TE;
    float* Tf2 = Tf1 + TE;
    float* Tf3 = Tf2 + TE;
    float* Tf4 = Tf3 + TE;
    short* Tb0 = (short*)(Tf4 + TE);
    short* Tb1 = Tb0 + TE;
    short* Tb2 = Tb1 + TE;
    short* Tb3 = Tb2 + TE;
    short* Tb4 = Tb3 + TE;

    const dim3 passGrid(NN / 64, SPLITS);
    const int cvtBlocks = (int)(TE / 4 / 256);        // 256
    const int cmbBlocks = (int)((TE / 4 + 255) / 256);

    // T0 = x -> bf16
    cvt_kernel<<<cvtBlocks, 256, 0, stream>>>(x, Tb0, (int)(TE / 4));

    // Pass 1: T1 = T0 @ L^T
    cheb_pass_kernel<<<passGrid, 256, 0, stream>>>(L, Tb0, part);
    combine_kernel<<<cmbBlocks, 256, 0, stream>>>(part, nullptr, 1.0f, 0, Tf1, Tb1);
    // Pass 2: T2 = 2*(T1 @ L^T) - T0
    cheb_pass_kernel<<<passGrid, 256, 0, stream>>>(L, Tb1, part);
    combine_kernel<<<cmbBlocks, 256, 0, stream>>>(part, x, 2.0f, 1, Tf2, Tb2);
    // Pass 3: T3 = 2*(T2 @ L^T) - T1
    cheb_pass_kernel<<<passGrid, 256, 0, stream>>>(L, Tb2, part);
    combine_kernel<<<cmbBlocks, 256, 0, stream>>>(part, Tf1, 2.0f, 1, Tf3, Tb3);
    // Pass 4: T4 = 2*(T3 @ L^T) - T2
    cheb_pass_kernel<<<passGrid, 256, 0, stream>>>(L, Tb3, part);
    combine_kernel<<<cmbBlocks, 256, 0, stream>>>(part, Tf2, 2.0f, 1, Tf4, Tb4);

    // Epilogue: y = einsum + bias
    final_kernel<<<(COUT / 4) * NN / 256, 256, 0, stream>>>(
        x, Tf1, Tf2, Tf3, Tf4, theta, bias, y);
}

// Round 2
// 286.323 us; speedup vs baseline: 1.0001x; 1.0001x over previous
//
#include <hip/hip_runtime.h>
#include <hip/hip_bf16.h>

#define NN 8192
#define CIN 32
#define COUT 64
#define KF 5
#define SPLITS 8

typedef __attribute__((ext_vector_type(8))) short bf16x8_t;
typedef __attribute__((ext_vector_type(4))) float f32x4_t;

// fp32 -> bf16 RNE (no NaN handling; inputs are finite Gaussians)
__device__ __forceinline__ short f2bf(float f) {
    unsigned u = __builtin_bit_cast(unsigned, f);
    unsigned r = (u + 0x7FFFu + ((u >> 16) & 1u)) >> 16;
    return (short)(unsigned short)r;
}

// Convert fp32 array -> bf16 (short) array, 4 elements/thread, grid-stride
__global__ void cvt_kernel(const float* __restrict__ src, short* __restrict__ dst,
                           long n4) {
    long stride = (long)gridDim.x * blockDim.x;
    for (long idx = blockIdx.x * (long)blockDim.x + threadIdx.x; idx < n4; idx += stride) {
        float4 v = reinterpret_cast<const float4*>(src)[idx];
        short4 b;
        b.x = f2bf(v.x); b.y = f2bf(v.y); b.z = f2bf(v.z); b.w = f2bf(v.w);
        reinterpret_cast<short4*>(dst)[idx] = b;
    }
}

// One Chebyshev GEMM pass, bf16 L (split-K partials):
//   part[s][c][i] = sum_{j in chunk s} Tcur[c][j] * Lb[i][j]
// Block = 4 waves; wave w owns i-tile [blockIdx.x*64 + w*16, +16), all 32 channels.
// MFMA 16x16x32 bf16: A = Tcur rows (M=c), B = L rows (N=i), K=j.
__global__ __launch_bounds__(256, 4) void cheb_pass_bf_kernel(
    const short* __restrict__ Lb,     // NN x NN bf16
    const short* __restrict__ Tcur,   // CIN x NN bf16
    float* __restrict__ part)         // SPLITS x CIN x NN fp32
{
    const int lane = threadIdx.x & 63;
    const int wave = threadIdx.x >> 6;
    const int g = lane >> 4;          // 0..3 (k-chunk group)
    const int r = lane & 15;          // row-within-16
    const int i0 = blockIdx.x * 64 + wave * 16;
    const int s = blockIdx.y;
    const int jb = s * (NN / SPLITS);

    const short* Lrow = Lb + (size_t)(i0 + r) * NN;

    f32x4_t acc0 = {0.f, 0.f, 0.f, 0.f};
    f32x4_t acc1 = {0.f, 0.f, 0.f, 0.f};

    for (int j = jb; j < jb + NN / SPLITS; j += 32) {
        const int jl = j + g * 8;
        bf16x8_t b  = *reinterpret_cast<const bf16x8_t*>(Lrow + jl);
        bf16x8_t a0 = *reinterpret_cast<const bf16x8_t*>(Tcur + (size_t)r * NN + jl);
        bf16x8_t a1 = *reinterpret_cast<const bf16x8_t*>(Tcur + (size_t)(r + 16) * NN + jl);
        acc0 = __builtin_amdgcn_mfma_f32_16x16x32_bf16(a0, b, acc0, 0, 0, 0);
        acc1 = __builtin_amdgcn_mfma_f32_16x16x32_bf16(a1, b, acc1, 0, 0, 0);
    }

    // D layout (m89-verified): col = lane&15 -> i, row = (lane>>4)*4 + reg -> c
    float* pbase = part + (size_t)s * CIN * NN + i0 + r;
#pragma unroll
    for (int t = 0; t < 4; ++t) {
        pbase[(size_t)(g * 4 + t) * NN]      = acc0[t];
        pbase[(size_t)(g * 4 + t + 16) * NN] = acc1[t];
    }
}

// Fallback pass reading fp32 L (only used if ws too small for Lb)
__global__ __launch_bounds__(256, 4) void cheb_pass_kernel(
    const float* __restrict__ L,
    const short* __restrict__ Tcur,
    float* __restrict__ part)
{
    const int lane = threadIdx.x & 63;
    const int wave = threadIdx.x >> 6;
    const int g = lane >> 4;
    const int r = lane & 15;
    const int i0 = blockIdx.x * 64 + wave * 16;
    const int s = blockIdx.y;
    const int jb = s * (NN / SPLITS);

    const float* Lrow = L + (size_t)(i0 + r) * NN;

    f32x4_t acc0 = {0.f, 0.f, 0.f, 0.f};
    f32x4_t acc1 = {0.f, 0.f, 0.f, 0.f};

    for (int j = jb; j < jb + NN / SPLITS; j += 32) {
        const int jl = j + g * 8;
        float4 l0 = *reinterpret_cast<const float4*>(Lrow + jl);
        float4 l1 = *reinterpret_cast<const float4*>(Lrow + jl + 4);
        bf16x8_t b;
        b[0] = f2bf(l0.x); b[1] = f2bf(l0.y); b[2] = f2bf(l0.z); b[3] = f2bf(l0.w);
        b[4] = f2bf(l1.x); b[5] = f2bf(l1.y); b[6] = f2bf(l1.z); b[7] = f2bf(l1.w);
        bf16x8_t a0 = *reinterpret_cast<const bf16x8_t*>(Tcur + (size_t)r * NN + jl);
        bf16x8_t a1 = *reinterpret_cast<const bf16x8_t*>(Tcur + (size_t)(r + 16) * NN + jl);
        acc0 = __builtin_amdgcn_mfma_f32_16x16x32_bf16(a0, b, acc0, 0, 0, 0);
        acc1 = __builtin_amdgcn_mfma_f32_16x16x32_bf16(a1, b, acc1, 0, 0, 0);
    }

    float* pbase = part + (size_t)s * CIN * NN + i0 + r;
#pragma unroll
    for (int t = 0; t < 4; ++t) {
        pbase[(size_t)(g * 4 + t) * NN]      = acc0[t];
        pbase[(size_t)(g * 4 + t + 16) * NN] = acc1[t];
    }
}

// T_next = alpha * sum_s part[s] - (has_prev ? T_prev : 0); write fp32 + bf16
__global__ void combine_kernel(const float* __restrict__ part,
                               const float* __restrict__ Tprev,
                               const float alpha, const int has_prev,
                               float* __restrict__ Tf, short* __restrict__ Tb)
{
    int idx = blockIdx.x * blockDim.x + threadIdx.x;  // quad index over CIN*NN/4
    if (idx >= CIN * NN / 4) return;
    const float4* p = reinterpret_cast<const float4*>(part);
    float4 sv = p[idx];
#pragma unroll
    for (int t = 1; t < SPLITS; ++t) {
        float4 v = p[(size_t)t * (CIN * NN / 4) + idx];
        sv.x += v.x; sv.y += v.y; sv.z += v.z; sv.w += v.w;
    }
    sv.x *= alpha; sv.y *= alpha; sv.z *= alpha; sv.w *= alpha;
    if (has_prev) {
        float4 pv = reinterpret_cast<const float4*>(Tprev)[idx];
        sv.x -= pv.x; sv.y -= pv.y; sv.z -= pv.z; sv.w -= pv.w;
    }
    reinterpret_cast<float4*>(Tf)[idx] = sv;
    short4 b;
    b.x = f2bf(sv.x); b.y = f2bf(sv.y); b.z = f2bf(sv.z); b.w = f2bf(sv.w);
    reinterpret_cast<short4*>(Tb)[idx] = b;
}

// y(o,i) = bias(o) + sum_{c,k} T_k(c,i) * theta(o,c,k); 4 o's per thread
__global__ __launch_bounds__(256) void final_kernel(
    const float* __restrict__ x,   // T0 (fp32, exact)
    const float* __restrict__ T1, const float* __restrict__ T2,
    const float* __restrict__ T3, const float* __restrict__ T4,
    const float* __restrict__ theta, const float* __restrict__ bias,
    float* __restrict__ y)
{
    __shared__ float th[4 * CIN * KF];
    int idx = blockIdx.x * blockDim.x + threadIdx.x;
    int i = idx & (NN - 1);
    int og = idx >> 13;               // 0..15 (block-uniform: 32 blocks per og)
    for (int t = threadIdx.x; t < 4 * CIN * KF; t += blockDim.x)
        th[t] = theta[og * 4 * CIN * KF + t];
    __syncthreads();

    float a0 = bias[og * 4 + 0], a1 = bias[og * 4 + 1];
    float a2 = bias[og * 4 + 2], a3 = bias[og * 4 + 3];
    for (int c = 0; c < CIN; ++c) {
        size_t o = (size_t)c * NN + i;
        float t0 = x[o], t1 = T1[o], t2 = T2[o], t3 = T3[o], t4 = T4[o];
#pragma unroll
        for (int oo = 0; oo < 4; ++oo) {
            const float* tc = &th[(oo * CIN + c) * KF];
            float v = t0 * tc[0] + t1 * tc[1] + t2 * tc[2] + t3 * tc[3] + t4 * tc[4];
            if (oo == 0) a0 += v; else if (oo == 1) a1 += v;
            else if (oo == 2) a2 += v; else a3 += v;
        }
    }
    y[(size_t)(og * 4 + 0) * NN + i] = a0;
    y[(size_t)(og * 4 + 1) * NN + i] = a1;
    y[(size_t)(og * 4 + 2) * NN + i] = a2;
    y[(size_t)(og * 4 + 3) * NN + i] = a3;
}

extern "C" void kernel_launch(void* const* d_in, const int* in_sizes, int n_in,
                              void* d_out, int out_size, void* d_ws, size_t ws_size,
                              hipStream_t stream) {
    const float* L     = (const float*)d_in[0];
    const float* x     = (const float*)d_in[1];
    const float* theta = (const float*)d_in[2];
    const float* bias  = (const float*)d_in[3];
    float* y = (float*)d_out;

    const size_t TE = (size_t)CIN * NN;
    const size_t LE = (size_t)NN * NN;

    // Workspace layout (bf16-L path, ~143 MB):
    //   Lb:   NN*NN bf16        (128 MB)
    //   part: SPLITS*CIN*NN f32 (8 MB)
    //   Tf1..Tf4: CIN*NN f32    (1 MB each)
    //   Tb0..Tb4: CIN*NN bf16   (0.5 MB each)
    const size_t need = LE * 2 + (SPLITS + 4) * TE * 4 + 5 * TE * 2;
    const bool use_bf_L = ws_size >= need;

    short* Lb;
    float* part;
    if (use_bf_L) {
        Lb   = (short*)d_ws;
        part = (float*)(Lb + LE);
    } else {
        Lb   = nullptr;
        part = (float*)d_ws;
    }
    float* Tf1 = part + (size_t)SPLITS * TE;
    float* Tf2 = Tf1 + TE;
    float* Tf3 = Tf2 + TE;
    float* Tf4 = Tf3 + TE;
    short* Tb0 = (short*)(Tf4 + TE);
    short* Tb1 = Tb0 + TE;
    short* Tb2 = Tb1 + TE;
    short* Tb3 = Tb2 + TE;
    short* Tb4 = Tb3 + TE;

    const dim3 passGrid(NN / 64, SPLITS);
    const int cmbBlocks = (int)((TE / 4 + 255) / 256);

    // T0 = x -> bf16
    cvt_kernel<<<(int)(TE / 4 / 256), 256, 0, stream>>>(x, Tb0, (long)(TE / 4));

    if (use_bf_L) {
        // L -> bf16 once (256 MB read + 128 MB write); Lb then L3-resident
        cvt_kernel<<<2048, 256, 0, stream>>>(L, Lb, (long)(LE / 4));

        cheb_pass_bf_kernel<<<passGrid, 256, 0, stream>>>(Lb, Tb0, part);
        combine_kernel<<<cmbBlocks, 256, 0, stream>>>(part, nullptr, 1.0f, 0, Tf1, Tb1);
        cheb_pass_bf_kernel<<<passGrid, 256, 0, stream>>>(Lb, Tb1, part);
        combine_kernel<<<cmbBlocks, 256, 0, stream>>>(part, x, 2.0f, 1, Tf2, Tb2);
        cheb_pass_bf_kernel<<<passGrid, 256, 0, stream>>>(Lb, Tb2, part);
        combine_kernel<<<cmbBlocks, 256, 0, stream>>>(part, Tf1, 2.0f, 1, Tf3, Tb3);
        cheb_pass_bf_kernel<<<passGrid, 256, 0, stream>>>(Lb, Tb3, part);
        combine_kernel<<<cmbBlocks, 256, 0, stream>>>(part, Tf2, 2.0f, 1, Tf4, Tb4);
    } else {
        cheb_pass_kernel<<<passGrid, 256, 0, stream>>>(L, Tb0, part);
        combine_kernel<<<cmbBlocks, 256, 0, stream>>>(part, nullptr, 1.0f, 0, Tf1, Tb1);
        cheb_pass_kernel<<<passGrid, 256, 0, stream>>>(L, Tb1, part);
        combine_kernel<<<cmbBlocks, 256, 0, stream>>>(part, x, 2.0f, 1, Tf2, Tb2);
        cheb_pass_kernel<<<passGrid, 256, 0, stream>>>(L, Tb2, part);
        combine_kernel<<<cmbBlocks, 256, 0, stream>>>(part, Tf1, 2.0f, 1, Tf3, Tb3);
        cheb_pass_kernel<<<passGrid, 256, 0, stream>>>(L, Tb3, part);
        combine_kernel<<<cmbBlocks, 256, 0, stream>>>(part, Tf2, 2.0f, 1, Tf4, Tb4);
    }

    // Epilogue: y = einsum + bias
    final_kernel<<<(COUT / 4) * NN / 256, 256, 0, stream>>>(
        x, Tf1, Tf2, Tf3, Tf4, theta, bias, y);
}